// Round 11
// baseline (109.721 us; speedup 1.0000x reference)
//
#include <hip/hip_runtime.h>
#include <hip/hip_bf16.h>
#include <hip/hip_fp16.h>
#include <math.h>

#define NPP   1024
#define BN    8192     // BS*N
#define NE    65536    // BN*KDEG

typedef __attribute__((ext_vector_type(8))) short bf16x8;
typedef __attribute__((ext_vector_type(4))) float f32x4;

__device__ __forceinline__ short f2bf(float f) {
  __hip_bfloat16 h = __float2bfloat16(f);
  return *reinterpret_cast<short*>(&h);
}
__device__ __forceinline__ float b2f(short h) {
  unsigned u = ((unsigned)(unsigned short)h) << 16;
  return __uint_as_float(u);
}
__device__ __forceinline__ unsigned short f2h(float f) {
  __half h = __float2half(f);
  return *reinterpret_cast<unsigned short*>(&h);
}
__device__ __forceinline__ float h2f(unsigned short u) {
  __half h = *reinterpret_cast<__half*>(&u);
  return __half2float(h);
}

// ---------------------------------------------------------------------------
// Kernel 1: three_nn + interpolation, one WAVE per fine point (passing).
// ---------------------------------------------------------------------------
__device__ __forceinline__ unsigned long long pkkey(float d, int j) {
  return ((unsigned long long)__float_as_uint(d) << 32) | (unsigned int)j;
}

__global__ __launch_bounds__(256) void interp_kernel(
    const float* __restrict__ h0, const float* __restrict__ h1,
    const float* __restrict__ uph0, const float* __restrict__ uph1,
    const float* __restrict__ xyz, const float* __restrict__ xyzp,
    float* __restrict__ h0c, float* __restrict__ h1c)
{
  const int tid  = threadIdx.x;
  const int lane = tid & 63;
  const int wid  = tid >> 6;
  const int fi   = blockIdx.x * 4 + wid;
  const int b    = fi >> 12;

  const float px = xyz[fi*3+0], py = xyz[fi*3+1], pz = xyz[fi*3+2];

  unsigned long long k0 = ~0ull, k1 = ~0ull, k2 = ~0ull;
  const float* cbase = xyzp + (size_t)b*NPP*3;
  #pragma unroll 4
  for (int j = lane; j < NPP; j += 64) {
    const float* cp = cbase + j*3;
    float ax = px - cp[0], ay = py - cp[1], az = pz - cp[2];
    float dd = fmaf(az, az, fmaf(ay, ay, ax*ax));
    unsigned long long kk = pkkey(dd, j);
    if (kk < k0)      { k2 = k1; k1 = k0; k0 = kk; }
    else if (kk < k1) { k2 = k1; k1 = kk; }
    else if (kk < k2) { k2 = kk; }
  }
  #pragma unroll
  for (int off = 1; off < 64; off <<= 1) {
    unsigned long long b0 = __shfl_xor(k0, off);
    unsigned long long b1 = __shfl_xor(k1, off);
    unsigned long long b2 = __shfl_xor(k2, off);
    unsigned long long c0, c1, c2;
    if (k0 <= b0) {
      c0 = k0;
      if (k1 <= b0) { c1 = k1; c2 = (k2 <= b0) ? k2 : b0; }
      else          { c1 = b0; c2 = (k1 <= b1) ? k1 : b1; }
    } else {
      c0 = b0;
      if (b1 <= k0) { c1 = b1; c2 = (b2 <= k0) ? b2 : k0; }
      else          { c1 = k0; c2 = (b1 <= k1) ? b1 : k1; }
    }
    k0 = c0; k1 = c1; k2 = c2;
  }
  const int i0 = (int)(k0 & 0xffffffffu);
  const int i1 = (int)(k1 & 0xffffffffu);
  const int i2 = (int)(k2 & 0xffffffffu);
  const float dd0 = __uint_as_float((unsigned)(k0 >> 32));
  const float dd1 = __uint_as_float((unsigned)(k1 >> 32));
  const float dd2 = __uint_as_float((unsigned)(k2 >> 32));

  float w0, w1v, w2v;
  {
    float s0 = sqrtf(fmaxf(dd0, 0.f));
    float s1 = sqrtf(fmaxf(dd1, 0.f));
    float s2 = sqrtf(fmaxf(dd2, 0.f));
    w0  = 1.f / (fmaxf(s0*s0, 1e-10f) + 1e-8f);
    w1v = 1.f / (fmaxf(s1*s1, 1e-10f) + 1e-8f);
    w2v = 1.f / (fmaxf(s2*s2, 1e-10f) + 1e-8f);
    float wsum = w0 + w1v + w2v;
    w0 /= wsum; w1v /= wsum; w2v /= wsum;
  }

  const float* u0 = uph0 + (size_t)b*NPP*16;
  const float* u1 = uph1 + (size_t)b*NPP*48;
  if (lane < 16) {
    int c = lane;
    h0c[(size_t)fi*32 + c] = w0*u0[i0*16+c] + w1v*u0[i1*16+c] + w2v*u0[i2*16+c];
    h0c[(size_t)fi*32 + 16 + c] = h0[(size_t)fi*16 + c];
  } else {
    int q = lane - 16;
    h1c[(size_t)fi*96 + q] = w0*u1[i0*48+q] + w1v*u1[i1*48+q] + w2v*u1[i2*48+q];
    h1c[(size_t)fi*96 + 48 + q] = h1[(size_t)fi*48 + q];
  }
}

// ---------------------------------------------------------------------------
// Kernel 1b: repack to bf16 (R8 layouts, unchanged).
// ---------------------------------------------------------------------------
__global__ __launch_bounds__(256) void repack_bf16(
    const float* __restrict__ w00, const float* __restrict__ w01,
    const float* __restrict__ w10, const float* __restrict__ w11,
    const float* __restrict__ w2_00, const float* __restrict__ w2_01,
    const float* __restrict__ w2_10, const float* __restrict__ w2_11,
    unsigned short* __restrict__ B00, unsigned short* __restrict__ B01,
    unsigned short* __restrict__ B10, unsigned short* __restrict__ B11,
    unsigned short* __restrict__ W2H, unsigned short* __restrict__ W2L)
{
  int idx = blockIdx.x * 256 + threadIdx.x;
  if (idx < 49152) {
    int a = idx & 16383;
    int i = a & 31, o = (a >> 5) & 15, k = a >> 9;
    int src = k*512 + o*32 + i;
    if (idx < 16384)      B00[a] = (unsigned short)f2bf(w00[src]);
    else if (idx < 32768) B01[a] = (unsigned short)f2bf(w01[src]);
    else                  B10[a] = (unsigned short)f2bf(w10[src]);
  } else if (idx < 98304) {
    int a = idx - 49152;                   // ((f*32+k)*16+o)*32+i
    int i = a & 31, o = (a >> 5) & 15, s = a >> 9;
    int f = s >> 5, k = s & 31;
    B11[a] = (unsigned short)f2bf(w11[k*1536 + (o*32+i)*3 + f]);
  } else if (idx < 102400) {
    int a = idx - 98304;                   // W2H: [p][b][a]
    int p = a >> 10, rem = a & 1023;
    int b = rem >> 5, aa = rem & 31;
    const float* w2p = p==0?w2_00 : p==1?w2_01 : p==2?w2_10 : w2_11;
    W2H[a] = (unsigned short)f2bf(w2p[aa*32 + b]);
  } else if (idx < 106496) {
    int a = idx - 102400;                  // W2L
    int p = a >> 10, rem = a & 1023;
    int b = rem >> 5, aa = rem & 31;
    const float* w2p = p==0?w2_00 : p==1?w2_01 : p==2?w2_10 : w2_11;
    float v = w2p[aa*32 + b];
    short h = f2bf(v);
    W2L[a] = (unsigned short)f2bf(v - b2f(h));
  }
}

// ---------------------------------------------------------------------------
// Kernel 2: MFMA edge kernel — R10 structure with the t-loop SPLIT across
// wave pairs: block = 8 waves = 4 edge-groups x 2 t-halves (th). Each wave
// handles 16 of the 32 k-channels (its half of the B-stream and of the x2
// table, which it also computes: 3 MLP MFMAs instead of 6). Partials are
// combined through the reused x2 LDS buffer (2 barriers). 8192 waves total
// -> full occupancy (grid was the limiter at 4096 waves).
// ---------------------------------------------------------------------------
struct EP {
  const float *r; const int *esrc;
  const float *b00, *b01, *b10, *b11;
  const float *w1_00, *b1_00, *b2_00;
  const float *w1_01, *b1_01, *b2_01;
  const float *w1_10, *b1_10, *b2_10;
  const float *w1_11, *b1_11, *b2_11;
  const unsigned short *B00, *B01, *B10, *B11, *W2H, *W2L;
  const float *h0c, *h1c;
  float *agg0, *agg1;
};

#define CVT4(PTR) ({ ushort4 u_ = *(const ushort4*)(PTR); \
    f32x4 r_; r_[0]=h2f(u_.x); r_[1]=h2f(u_.y); r_[2]=h2f(u_.z); r_[3]=h2f(u_.w); r_; })

__global__ __launch_bounds__(512) void edge_mfma(EP P)
{
  // x2 table: [tloc(16)][w(8)][p(4)][e(16)] f16, row stride 544 shorts.
  // Reused after the GEMM loops as the f32 partial-reduction buffer
  // (4 eg x 64 lanes x 17 floats = 17408 B, exactly the same footprint).
  __shared__ __align__(16) unsigned short x2Lh[16*544];

  const int tid  = threadIdx.x;
  const int w    = tid >> 6;        // 0..7
  const int lane = tid & 63;
  const int el   = lane & 15;
  const int kg   = lane >> 4;
  const int kg4  = kg << 2;
  const int isl  = kg * 8;
  const int eg   = w >> 1;          // edge-group 0..3
  const int th   = w & 1;           // t-half 0..1
  const int eb   = blockIdx.x * 64 + eg * 16;
  const int e    = eb + el;
  const int ch   = th*16 + el;      // this wave's MLP output channel
  const int tb   = th * 16;         // global t base for this wave

  const int   sidx = P.esrc[e];
  const float rv   = P.r[e];

  const f32x4 zero4 = {0.f, 0.f, 0.f, 0.f};

  // ---- radial MLPs: only this wave's 16 channels (3 MFMAs per path) ----
  #pragma unroll
  for (int p = 0; p < 4; ++p) {
    const float* w1p = p==0?P.w1_00 : p==1?P.w1_01 : p==2?P.w1_10 : P.w1_11;
    const float* b1p = p==0?P.b1_00 : p==1?P.b1_01 : p==2?P.b1_10 : P.b1_11;
    const float* b2p = p==0?P.b2_00 : p==1?P.b2_01 : p==2?P.b2_10 : P.b2_11;
    const unsigned short* bhp = P.W2H + p*1024 + ch*32 + isl;
    const unsigned short* blp = P.W2L + p*1024 + ch*32 + isl;
    f32x4 wa  = *(const f32x4*)(w1p + isl);
    f32x4 wb  = *(const f32x4*)(w1p + isl + 4);
    f32x4 ba  = *(const f32x4*)(b1p + isl);
    f32x4 bbv = *(const f32x4*)(b1p + isl + 4);
    bf16x8 bh = *(const bf16x8*)bhp;
    bf16x8 bl = *(const bf16x8*)blp;
    float b2v = b2p[ch];
    bf16x8 axh, axl;
    #pragma unroll
    for (int j = 0; j < 4; ++j) {
      float v0 = fmaxf(fmaf(rv, wa[j], ba[j]),  0.f);
      float v1 = fmaxf(fmaf(rv, wb[j], bbv[j]), 0.f);
      short h0s = f2bf(v0), h1s_ = f2bf(v1);
      axh[j]   = h0s;  axl[j]   = f2bf(v0 - b2f(h0s));
      axh[j+4] = h1s_; axl[j+4] = f2bf(v1 - b2f(h1s_));
    }
    f32x4 z = __builtin_amdgcn_mfma_f32_16x16x32_bf16(axl, bh, zero4, 0,0,0);
    z = __builtin_amdgcn_mfma_f32_16x16x32_bf16(axh, bl, z, 0,0,0);
    z = __builtin_amdgcn_mfma_f32_16x16x32_bf16(axh, bh, z, 0,0,0);
    ushort4 ov;
    ov.x = f2h(fmaxf(z[0] + b2v, 0.f));
    ov.y = f2h(fmaxf(z[1] + b2v, 0.f));
    ov.z = f2h(fmaxf(z[2] + b2v, 0.f));
    ov.w = f2h(fmaxf(z[3] + b2v, 0.f));
    *(ushort4*)&x2Lh[el*544 + w*64 + p*16 + kg4] = ov;   // row tloc = el
  }
  // no barrier: each wave reads only its own w-slots (in-order LDS)

  // ---- A-side feature slices ----
  f32x4 h0a = *(const f32x4*)(P.h0c + (size_t)sidx*32 + isl);
  f32x4 h0b = *(const f32x4*)(P.h0c + (size_t)sidx*32 + isl + 4);
  float h1sl[24];
  {
    const float* hp = P.h1c + (size_t)sidx*96 + isl*3;
    #pragma unroll
    for (int q = 0; q < 6; ++q) {
      f32x4 v = *(const f32x4*)(hp + q*4);
      h1sl[q*4+0]=v[0]; h1sl[q*4+1]=v[1]; h1sl[q*4+2]=v[2]; h1sl[q*4+3]=v[3];
    }
  }

  bf16x8 a_h0;
  #pragma unroll
  for (int j = 0; j < 4; ++j) { a_h0[j] = f2bf(h0a[j]); a_h0[j+4] = f2bf(h0b[j]); }

  const int xrow = w*64 + kg4;   // + p*16 -> slot of x2_p[edge kg4+r]

  // ---------------- P00: msg0 = b00 * (R00 . hs0), t-half ----------------
  f32x4 macc0 = zero4;
  {
    const unsigned short* bb = P.B00 + (size_t)tb*512 + el*32 + isl;
    #pragma unroll 4
    for (int t = 0; t < 16; ++t) {
      bf16x8 bv = *(const bf16x8*)(bb + t*512);
      f32x4 z = __builtin_amdgcn_mfma_f32_16x16x32_bf16(a_h0, bv, zero4, 0, 0, 0);
      f32x4 xs = CVT4(&x2Lh[t*544 + xrow + 0]);             // path 0
      macc0[0] = fmaf(xs[0], z[0], macc0[0]);
      macc0[1] = fmaf(xs[1], z[1], macc0[1]);
      macc0[2] = fmaf(xs[2], z[2], macc0[2]);
      macc0[3] = fmaf(xs[3], z[3], macc0[3]);
    }
  }
  { // scale partial by b00 (linear in the t-split)
    f32x4 bv = *(const f32x4*)(P.b00 + eb + kg4);
    macc0[0]*=bv[0]; macc0[1]*=bv[1]; macc0[2]*=bv[2]; macc0[3]*=bv[3];
  }

  // ---------------- P10: msg0 += R10 . t10, t-half ----------------
  {
    const float* bp = P.b10 + (size_t)e*3;
    float c0 = bp[0], c1 = bp[1], c2 = bp[2];
    bf16x8 a_t;
    #pragma unroll
    for (int j = 0; j < 8; ++j)
      a_t[j] = f2bf(c0*h1sl[j*3+0] + c1*h1sl[j*3+1] + c2*h1sl[j*3+2]);
    const unsigned short* bb = P.B10 + (size_t)tb*512 + el*32 + isl;
    #pragma unroll 4
    for (int t = 0; t < 16; ++t) {
      bf16x8 bv = *(const bf16x8*)(bb + t*512);
      f32x4 z = __builtin_amdgcn_mfma_f32_16x16x32_bf16(a_t, bv, zero4, 0, 0, 0);
      f32x4 xs = CVT4(&x2Lh[t*544 + xrow + 32]);            // path 2
      macc0[0] = fmaf(xs[0], z[0], macc0[0]);
      macc0[1] = fmaf(xs[1], z[1], macc0[1]);
      macc0[2] = fmaf(xs[2], z[2], macc0[2]);
      macc0[3] = fmaf(xs[3], z[3], macc0[3]);
    }
  }

  // ---------------- P01: msg1 = b01[m] * (R01 . hs0), t-half ----------------
  f32x4 c01 = zero4;
  {
    const unsigned short* bb = P.B01 + (size_t)tb*512 + el*32 + isl;
    #pragma unroll 4
    for (int t = 0; t < 16; ++t) {
      bf16x8 bv = *(const bf16x8*)(bb + t*512);
      f32x4 z = __builtin_amdgcn_mfma_f32_16x16x32_bf16(a_h0, bv, zero4, 0, 0, 0);
      f32x4 xs = CVT4(&x2Lh[t*544 + xrow + 16]);            // path 1
      c01[0] = fmaf(xs[0], z[0], c01[0]);
      c01[1] = fmaf(xs[1], z[1], c01[1]);
      c01[2] = fmaf(xs[2], z[2], c01[2]);
      c01[3] = fmaf(xs[3], z[3], c01[3]);
    }
  }
  f32x4 m1a, m1b, m1c;
  {
    const float* bp = P.b01 + (size_t)(eb + kg4)*3;   // rows kg4..kg4+3
    f32x4 q0 = *(const f32x4*)(bp);
    f32x4 q1 = *(const f32x4*)(bp + 4);
    f32x4 q2 = *(const f32x4*)(bp + 8);
    m1a[0]=c01[0]*q0[0]; m1a[1]=c01[1]*q0[3]; m1a[2]=c01[2]*q1[2]; m1a[3]=c01[3]*q2[1];
    m1b[0]=c01[0]*q0[1]; m1b[1]=c01[1]*q1[0]; m1b[2]=c01[2]*q1[3]; m1b[3]=c01[3]*q2[2];
    m1c[0]=c01[0]*q0[2]; m1c[1]=c01[1]*q1[1]; m1c[2]=c01[2]*q2[0]; m1c[3]=c01[3]*q2[3];
  }

  // ---------------- P11: msg1 += sum_f R11f . tmp_f, t-half ----------------
  {
    const float* b11e = P.b11 + (size_t)e*27;
    #pragma unroll 1
    for (int f = 0; f < 3; ++f) {
      float bm[9];
      #pragma unroll
      for (int mn = 0; mn < 9; ++mn) bm[mn] = b11e[mn*3 + f];
      bf16x8 am0, am1, am2;
      #pragma unroll
      for (int j = 0; j < 8; ++j) {
        float hn0 = h1sl[j*3+0], hn1 = h1sl[j*3+1], hn2 = h1sl[j*3+2];
        am0[j] = f2bf(bm[0]*hn0 + bm[1]*hn1 + bm[2]*hn2);
        am1[j] = f2bf(bm[3]*hn0 + bm[4]*hn1 + bm[5]*hn2);
        am2[j] = f2bf(bm[6]*hn0 + bm[7]*hn1 + bm[8]*hn2);
      }
      const unsigned short* bb = P.B11 + (size_t)f*16384 + (size_t)tb*512 + el*32 + isl;
      #pragma unroll 4
      for (int t = 0; t < 16; ++t) {
        bf16x8 bv = *(const bf16x8*)(bb + t*512);
        f32x4 z0 = __builtin_amdgcn_mfma_f32_16x16x32_bf16(am0, bv, zero4, 0, 0, 0);
        f32x4 z1 = __builtin_amdgcn_mfma_f32_16x16x32_bf16(am1, bv, zero4, 0, 0, 0);
        f32x4 z2 = __builtin_amdgcn_mfma_f32_16x16x32_bf16(am2, bv, zero4, 0, 0, 0);
        f32x4 xs = CVT4(&x2Lh[t*544 + xrow + 48]);          // path 3
        m1a[0] = fmaf(xs[0], z0[0], m1a[0]);
        m1a[1] = fmaf(xs[1], z0[1], m1a[1]);
        m1a[2] = fmaf(xs[2], z0[2], m1a[2]);
        m1a[3] = fmaf(xs[3], z0[3], m1a[3]);
        m1b[0] = fmaf(xs[0], z1[0], m1b[0]);
        m1b[1] = fmaf(xs[1], z1[1], m1b[1]);
        m1b[2] = fmaf(xs[2], z1[2], m1b[2]);
        m1b[3] = fmaf(xs[3], z1[3], m1b[3]);
        m1c[0] = fmaf(xs[0], z2[0], m1c[0]);
        m1c[1] = fmaf(xs[1], z2[1], m1c[1]);
        m1c[2] = fmaf(xs[2], z2[2], m1c[2]);
        m1c[3] = fmaf(xs[3], z2[3], m1c[3]);
      }
    }
  }

  // ---------------- combine t-halves, then per-dst means ----------------
  __syncthreads();                      // all x2 reads done -> reuse buffer
  float* red = (float*)x2Lh;
  const int rbase = (eg*64 + lane)*17;  // stride 17 floats: conflict-free
  if (th == 1) {
    float* rp = red + rbase;
    rp[0]=macc0[0]; rp[1]=macc0[1]; rp[2]=macc0[2]; rp[3]=macc0[3];
    rp[4]=m1a[0]; rp[5]=m1a[1]; rp[6]=m1a[2]; rp[7]=m1a[3];
    rp[8]=m1b[0]; rp[9]=m1b[1]; rp[10]=m1b[2]; rp[11]=m1b[3];
    rp[12]=m1c[0]; rp[13]=m1c[1]; rp[14]=m1c[2]; rp[15]=m1c[3];
  }
  __syncthreads();
  if (th == 0) {
    const float* rp = red + rbase;
    macc0[0]+=rp[0]; macc0[1]+=rp[1]; macc0[2]+=rp[2]; macc0[3]+=rp[3];
    m1a[0]+=rp[4]; m1a[1]+=rp[5]; m1a[2]+=rp[6]; m1a[3]+=rp[7];
    m1b[0]+=rp[8]; m1b[1]+=rp[9]; m1b[2]+=rp[10]; m1b[3]+=rp[11];
    m1c[0]+=rp[12]; m1c[1]+=rp[13]; m1c[2]+=rp[14]; m1c[3]+=rp[15];

    float s = macc0[0]+macc0[1]+macc0[2]+macc0[3];
    s += __shfl_xor(s, 16);
    if ((kg & 1) == 0)
      P.agg0[(size_t)((eb >> 3) + (kg >> 1))*16 + el] = s * 0.125f;

    float sa = m1a[0]+m1a[1]+m1a[2]+m1a[3]; sa += __shfl_xor(sa, 16);
    float sb = m1b[0]+m1b[1]+m1b[2]+m1b[3]; sb += __shfl_xor(sb, 16);
    float sc = m1c[0]+m1c[1]+m1c[2]+m1c[3]; sc += __shfl_xor(sc, 16);
    if ((kg & 1) == 0) {
      float* p = P.agg1 + (size_t)((eb >> 3) + (kg >> 1))*48 + el*3;
      p[0] = sa * 0.125f; p[1] = sb * 0.125f; p[2] = sc * 0.125f;
    }
  }
}

// ---------------------------------------------------------------------------
// Kernel 3: self-interaction + GNormSE3, 4 lanes per node (passing).
// ---------------------------------------------------------------------------
__global__ __launch_bounds__(256) void gnorm_kernel(
    const float* __restrict__ agg0, const float* __restrict__ agg1,
    const float* __restrict__ h0c, const float* __restrict__ h1c,
    const float* __restrict__ ws0, const float* __restrict__ ws1,
    const float* __restrict__ g0, const float* __restrict__ be0,
    const float* __restrict__ g1, const float* __restrict__ be1,
    float* __restrict__ out)
{
  const int gt  = blockIdx.x * 256 + threadIdx.x;
  const int fi  = gt >> 2;
  const int t4  = gt & 3;
  const int ob  = t4 * 4;

  const float* h0p = h0c + (size_t)fi*32;
  const float* h1p = h1c + (size_t)fi*96;

  float o0[4];
  #pragma unroll
  for (int oo = 0; oo < 4; ++oo) {
    int o = ob + oo;
    float a = agg0[(size_t)fi*16 + o];
    #pragma unroll
    for (int i = 0; i < 32; ++i)
      a = fmaf(ws0[o*32+i], h0p[i], a);
    o0[oo] = a;
  }
  {
    float n0[4], lmu = 0.f;
    #pragma unroll
    for (int oo = 0; oo < 4; ++oo) { n0[oo] = sqrtf(fmaf(o0[oo], o0[oo], 1e-12f)); lmu += n0[oo]; }
    lmu += __shfl_xor(lmu, 1); lmu += __shfl_xor(lmu, 2);
    float mu = lmu * 0.0625f;
    float lv = 0.f;
    #pragma unroll
    for (int oo = 0; oo < 4; ++oo) { float d = n0[oo]-mu; lv = fmaf(d, d, lv); }
    lv += __shfl_xor(lv, 1); lv += __shfl_xor(lv, 2);
    float inv = 1.f / sqrtf(lv * 0.0625f + 1e-5f);
    #pragma unroll
    for (int oo = 0; oo < 4; ++oo) {
      int o = ob + oo;
      float t = fmaxf(fmaf((n0[oo]-mu)*inv, g0[o], be0[o]), 0.f);
      out[(size_t)fi*16 + o] = t * (o0[oo] / n0[oo]);
    }
  }

  float o1[12];
  #pragma unroll
  for (int oo = 0; oo < 4; ++oo) {
    int o = ob + oo;
    float a0 = agg1[(size_t)fi*48 + o*3+0];
    float a1 = agg1[(size_t)fi*48 + o*3+1];
    float a2 = agg1[(size_t)fi*48 + o*3+2];
    #pragma unroll
    for (int i = 0; i < 32; ++i) {
      float wv = ws1[o*32+i];
      a0 = fmaf(wv, h1p[i*3+0], a0);
      a1 = fmaf(wv, h1p[i*3+1], a1);
      a2 = fmaf(wv, h1p[i*3+2], a2);
    }
    o1[oo*3+0] = a0; o1[oo*3+1] = a1; o1[oo*3+2] = a2;
  }
  {
    float n1[4], lmu = 0.f;
    #pragma unroll
    for (int oo = 0; oo < 4; ++oo) {
      float s = fmaf(o1[oo*3+0], o1[oo*3+0], 1e-12f);
      s = fmaf(o1[oo*3+1], o1[oo*3+1], s);
      s = fmaf(o1[oo*3+2], o1[oo*3+2], s);
      n1[oo] = sqrtf(s); lmu += n1[oo];
    }
    lmu += __shfl_xor(lmu, 1); lmu += __shfl_xor(lmu, 2);
    float mu = lmu * 0.0625f;
    float lv = 0.f;
    #pragma unroll
    for (int oo = 0; oo < 4; ++oo) { float d = n1[oo]-mu; lv = fmaf(d, d, lv); }
    lv += __shfl_xor(lv, 1); lv += __shfl_xor(lv, 2);
    float inv = 1.f / sqrtf(lv * 0.0625f + 1e-5f);
    float* out1 = out + (size_t)BN*16;
    #pragma unroll
    for (int oo = 0; oo < 4; ++oo) {
      int o = ob + oo;
      float t = fmaxf(fmaf((n1[oo]-mu)*inv, g1[o], be1[o]), 0.f);
      #pragma unroll
      for (int m = 0; m < 3; ++m)
        out1[(size_t)fi*48 + o*3+m] = t * (o1[oo*3+m] / n1[oo]);
    }
  }
}

// ---------------------------------------------------------------------------
extern "C" void kernel_launch(void* const* d_in, const int* in_sizes, int n_in,
                              void* d_out, int out_size, void* d_ws, size_t ws_size,
                              hipStream_t stream)
{
  (void)in_sizes; (void)n_in; (void)out_size; (void)ws_size;
  const float* h0   = (const float*)d_in[0];
  const float* h1   = (const float*)d_in[1];
  const float* uph0 = (const float*)d_in[2];
  const float* uph1 = (const float*)d_in[3];
  const float* xyz  = (const float*)d_in[4];
  const float* xyzp = (const float*)d_in[5];
  const int*   esrc = (const int*)d_in[6];
  // d_in[7] = edge_dst: structurally e>>3; not needed.
  const float* rr   = (const float*)d_in[8];

  float* wsp  = (float*)d_ws;
  float* h0c  = wsp;                          // BN*32
  float* h1c  = h0c + (size_t)BN*32;          // BN*96
  float* agg0 = h1c + (size_t)BN*96;          // BN*16
  float* agg1 = agg0 + (size_t)BN*16;         // BN*48
  unsigned short* B00 = (unsigned short*)(agg1 + (size_t)BN*48);
  unsigned short* B01 = B00 + 16384;
  unsigned short* B10 = B01 + 16384;
  unsigned short* B11 = B10 + 16384;          // 49152
  unsigned short* W2H = B11 + 49152;          // 4096
  unsigned short* W2L = W2H + 4096;           // 4096

  interp_kernel<<<BN/4, 256, 0, stream>>>(h0, h1, uph0, uph1, xyz, xyzp, h0c, h1c);
  repack_bf16<<<416, 256, 0, stream>>>(
      (const float*)d_in[17], (const float*)d_in[22],
      (const float*)d_in[27], (const float*)d_in[32],
      (const float*)d_in[15], (const float*)d_in[20],
      (const float*)d_in[25], (const float*)d_in[30],
      B00, B01, B10, B11, W2H, W2L);

  EP P;
  P.r = rr; P.esrc = esrc;
  P.b00 = (const float*)d_in[9];  P.b01 = (const float*)d_in[10];
  P.b10 = (const float*)d_in[11]; P.b11 = (const float*)d_in[12];
  P.w1_00 = (const float*)d_in[13]; P.b1_00 = (const float*)d_in[14]; P.b2_00 = (const float*)d_in[16];
  P.w1_01 = (const float*)d_in[18]; P.b1_01 = (const float*)d_in[19]; P.b2_01 = (const float*)d_in[21];
  P.w1_10 = (const float*)d_in[23]; P.b1_10 = (const float*)d_in[24]; P.b2_10 = (const float*)d_in[26];
  P.w1_11 = (const float*)d_in[28]; P.b1_11 = (const float*)d_in[29]; P.b2_11 = (const float*)d_in[31];
  P.B00 = B00; P.B01 = B01; P.B10 = B10; P.B11 = B11; P.W2H = W2H; P.W2L = W2L;
  P.h0c = h0c; P.h1c = h1c; P.agg0 = agg0; P.agg1 = agg1;

  edge_mfma<<<NE/64, 512, 0, stream>>>(P);

  gnorm_kernel<<<BN*4/256, 256, 0, stream>>>(agg0, agg1, h0c, h1c,
      (const float*)d_in[33], (const float*)d_in[34],
      (const float*)d_in[35], (const float*)d_in[36],
      (const float*)d_in[37], (const float*)d_in[38],
      (float*)d_out);
}

// Round 12
// 103.154 us; speedup vs baseline: 1.0637x; 1.0637x over previous
//
#include <hip/hip_runtime.h>
#include <hip/hip_bf16.h>
#include <hip/hip_fp16.h>
#include <math.h>

#define NPP   1024
#define BN    8192     // BS*N
#define NE    65536    // BN*KDEG

typedef __attribute__((ext_vector_type(8))) short bf16x8;
typedef __attribute__((ext_vector_type(4))) float f32x4;

__device__ __forceinline__ short f2bf(float f) {
  __hip_bfloat16 h = __float2bfloat16(f);
  return *reinterpret_cast<short*>(&h);
}
__device__ __forceinline__ float b2f(short h) {
  unsigned u = ((unsigned)(unsigned short)h) << 16;
  return __uint_as_float(u);
}
__device__ __forceinline__ unsigned short f2h(float f) {
  __half h = __float2half(f);
  return *reinterpret_cast<unsigned short*>(&h);
}
__device__ __forceinline__ float h2f(unsigned short u) {
  __half h = *reinterpret_cast<__half*>(&u);
  return __half2float(h);
}

// ---------------------------------------------------------------------------
// Kernel 1 (fused prologue): blocks [0,2048) = three_nn+interp (wave/point);
// blocks [2048,2464) = weight repack to bf16. Independent outputs, no LDS.
// ---------------------------------------------------------------------------
__device__ __forceinline__ unsigned long long pkkey(float d, int j) {
  return ((unsigned long long)__float_as_uint(d) << 32) | (unsigned int)j;
}

__global__ __launch_bounds__(256) void prolog_kernel(
    const float* __restrict__ h0, const float* __restrict__ h1,
    const float* __restrict__ uph0, const float* __restrict__ uph1,
    const float* __restrict__ xyz, const float* __restrict__ xyzp,
    float* __restrict__ h0c, float* __restrict__ h1c,
    const float* __restrict__ w00, const float* __restrict__ w01,
    const float* __restrict__ w10, const float* __restrict__ w11,
    const float* __restrict__ w2_00, const float* __restrict__ w2_01,
    const float* __restrict__ w2_10, const float* __restrict__ w2_11,
    unsigned short* __restrict__ B00, unsigned short* __restrict__ B01,
    unsigned short* __restrict__ B10, unsigned short* __restrict__ B11,
    unsigned short* __restrict__ W2H, unsigned short* __restrict__ W2L)
{
  const int tid = threadIdx.x;
  if (blockIdx.x >= BN/4) {
    // ---------------- repack branch ----------------
    int idx = (blockIdx.x - BN/4) * 256 + tid;
    if (idx < 49152) {
      int a = idx & 16383;
      int i = a & 31, o = (a >> 5) & 15, k = a >> 9;
      int src = k*512 + o*32 + i;
      if (idx < 16384)      B00[a] = (unsigned short)f2bf(w00[src]);
      else if (idx < 32768) B01[a] = (unsigned short)f2bf(w01[src]);
      else                  B10[a] = (unsigned short)f2bf(w10[src]);
    } else if (idx < 98304) {
      int a = idx - 49152;                   // ((f*32+k)*16+o)*32+i
      int i = a & 31, o = (a >> 5) & 15, s = a >> 9;
      int f = s >> 5, k = s & 31;
      B11[a] = (unsigned short)f2bf(w11[k*1536 + (o*32+i)*3 + f]);
    } else if (idx < 102400) {
      int a = idx - 98304;                   // W2H: [p][b][a]
      int p = a >> 10, rem = a & 1023;
      int b = rem >> 5, aa = rem & 31;
      const float* w2p = p==0?w2_00 : p==1?w2_01 : p==2?w2_10 : w2_11;
      W2H[a] = (unsigned short)f2bf(w2p[aa*32 + b]);
    } else if (idx < 106496) {
      int a = idx - 102400;                  // W2L
      int p = a >> 10, rem = a & 1023;
      int b = rem >> 5, aa = rem & 31;
      const float* w2p = p==0?w2_00 : p==1?w2_01 : p==2?w2_10 : w2_11;
      float v = w2p[aa*32 + b];
      short h = f2bf(v);
      W2L[a] = (unsigned short)f2bf(v - b2f(h));
    }
    return;
  }

  // ---------------- interp branch (wave per fine point) ----------------
  const int lane = tid & 63;
  const int wid  = tid >> 6;
  const int fi   = blockIdx.x * 4 + wid;
  const int b    = fi >> 12;

  const float px = xyz[fi*3+0], py = xyz[fi*3+1], pz = xyz[fi*3+2];

  unsigned long long k0 = ~0ull, k1 = ~0ull, k2 = ~0ull;
  const float* cbase = xyzp + (size_t)b*NPP*3;
  #pragma unroll 4
  for (int j = lane; j < NPP; j += 64) {
    const float* cp = cbase + j*3;
    float ax = px - cp[0], ay = py - cp[1], az = pz - cp[2];
    float dd = fmaf(az, az, fmaf(ay, ay, ax*ax));
    unsigned long long kk = pkkey(dd, j);
    if (kk < k0)      { k2 = k1; k1 = k0; k0 = kk; }
    else if (kk < k1) { k2 = k1; k1 = kk; }
    else if (kk < k2) { k2 = kk; }
  }
  #pragma unroll
  for (int off = 1; off < 64; off <<= 1) {
    unsigned long long b0 = __shfl_xor(k0, off);
    unsigned long long b1 = __shfl_xor(k1, off);
    unsigned long long b2 = __shfl_xor(k2, off);
    unsigned long long c0, c1, c2;
    if (k0 <= b0) {
      c0 = k0;
      if (k1 <= b0) { c1 = k1; c2 = (k2 <= b0) ? k2 : b0; }
      else          { c1 = b0; c2 = (k1 <= b1) ? k1 : b1; }
    } else {
      c0 = b0;
      if (b1 <= k0) { c1 = b1; c2 = (b2 <= k0) ? b2 : k0; }
      else          { c1 = k0; c2 = (b1 <= k1) ? b1 : k1; }
    }
    k0 = c0; k1 = c1; k2 = c2;
  }
  const int i0 = (int)(k0 & 0xffffffffu);
  const int i1 = (int)(k1 & 0xffffffffu);
  const int i2 = (int)(k2 & 0xffffffffu);
  const float dd0 = __uint_as_float((unsigned)(k0 >> 32));
  const float dd1 = __uint_as_float((unsigned)(k1 >> 32));
  const float dd2 = __uint_as_float((unsigned)(k2 >> 32));

  float w0, w1v, w2v;
  {
    float s0 = sqrtf(fmaxf(dd0, 0.f));
    float s1 = sqrtf(fmaxf(dd1, 0.f));
    float s2 = sqrtf(fmaxf(dd2, 0.f));
    w0  = 1.f / (fmaxf(s0*s0, 1e-10f) + 1e-8f);
    w1v = 1.f / (fmaxf(s1*s1, 1e-10f) + 1e-8f);
    w2v = 1.f / (fmaxf(s2*s2, 1e-10f) + 1e-8f);
    float wsum = w0 + w1v + w2v;
    w0 /= wsum; w1v /= wsum; w2v /= wsum;
  }

  const float* u0 = uph0 + (size_t)b*NPP*16;
  const float* u1 = uph1 + (size_t)b*NPP*48;
  if (lane < 16) {
    int c = lane;
    h0c[(size_t)fi*32 + c] = w0*u0[i0*16+c] + w1v*u0[i1*16+c] + w2v*u0[i2*16+c];
    h0c[(size_t)fi*32 + 16 + c] = h0[(size_t)fi*16 + c];
  } else {
    int q = lane - 16;
    h1c[(size_t)fi*96 + q] = w0*u1[i0*48+q] + w1v*u1[i1*48+q] + w2v*u1[i2*48+q];
    h1c[(size_t)fi*96 + 48 + q] = h1[(size_t)fi*48 + q];
  }
}

// ---------------------------------------------------------------------------
// Kernel 2: MFMA edge kernel — R10 verbatim (best measured: 76.3 us).
// Wave = 16 edges, 4 waves/block; x2 table f16 in LDS (16.9 KB);
// radial-MLP layer2 via split-precision MFMA (hi/lo bf16).
// ---------------------------------------------------------------------------
struct EP {
  const float *r; const int *esrc;
  const float *b00, *b01, *b10, *b11;
  const float *w1_00, *b1_00, *b2_00;
  const float *w1_01, *b1_01, *b2_01;
  const float *w1_10, *b1_10, *b2_10;
  const float *w1_11, *b1_11, *b2_11;
  const unsigned short *B00, *B01, *B10, *B11, *W2H, *W2L;
  const float *h0c, *h1c;
  float *agg0, *agg1;
};

#define CVT4(PTR) ({ ushort4 u_ = *(const ushort4*)(PTR); \
    f32x4 r_; r_[0]=h2f(u_.x); r_[1]=h2f(u_.y); r_[2]=h2f(u_.z); r_[3]=h2f(u_.w); r_; })

__global__ __launch_bounds__(256) void edge_mfma(EP P)
{
  // [t(32 ch)][wid(4)][p(4)][e(16)] f16, row stride 264 shorts (pad 8)
  __shared__ __align__(16) unsigned short x2Lh[32*264];

  const int tid  = threadIdx.x;
  const int wid  = tid >> 6;
  const int lane = tid & 63;
  const int el   = lane & 15;
  const int kg   = lane >> 4;
  const int kg4  = kg << 2;
  const int eb   = blockIdx.x * 64 + wid * 16;
  const int e    = eb + el;
  const int isl  = kg * 8;

  const int   sidx = P.esrc[e];
  const float rv   = P.r[e];

  const f32x4 zero4 = {0.f, 0.f, 0.f, 0.f};

  // ---- radial MLPs via split-precision MFMA, x2 -> f16 LDS table ----
  #pragma unroll
  for (int p = 0; p < 4; ++p) {
    const float* w1p = p==0?P.w1_00 : p==1?P.w1_01 : p==2?P.w1_10 : P.w1_11;
    const float* b1p = p==0?P.b1_00 : p==1?P.b1_01 : p==2?P.b1_10 : P.b1_11;
    const float* b2p = p==0?P.b2_00 : p==1?P.b2_01 : p==2?P.b2_10 : P.b2_11;
    const unsigned short* w2hp = P.W2H + p*1024;
    const unsigned short* w2lp = P.W2L + p*1024;
    f32x4 wa  = *(const f32x4*)(w1p + isl);
    f32x4 wb  = *(const f32x4*)(w1p + isl + 4);
    f32x4 ba  = *(const f32x4*)(b1p + isl);
    f32x4 bbv = *(const f32x4*)(b1p + isl + 4);
    bf16x8 bh0 = *(const bf16x8*)(w2hp + el*32 + isl);
    bf16x8 bh1 = *(const bf16x8*)(w2hp + (16+el)*32 + isl);
    bf16x8 bl0 = *(const bf16x8*)(w2lp + el*32 + isl);
    bf16x8 bl1 = *(const bf16x8*)(w2lp + (16+el)*32 + isl);
    float b2v0 = b2p[el];
    float b2v1 = b2p[16 + el];
    bf16x8 axh, axl;
    #pragma unroll
    for (int j = 0; j < 4; ++j) {
      float v0 = fmaxf(fmaf(rv, wa[j], ba[j]),  0.f);
      float v1 = fmaxf(fmaf(rv, wb[j], bbv[j]), 0.f);
      short h0s = f2bf(v0), h1s_ = f2bf(v1);
      axh[j]   = h0s;  axl[j]   = f2bf(v0 - b2f(h0s));
      axh[j+4] = h1s_; axl[j+4] = f2bf(v1 - b2f(h1s_));
    }
    f32x4 z0 = __builtin_amdgcn_mfma_f32_16x16x32_bf16(axl, bh0, zero4, 0,0,0);
    z0 = __builtin_amdgcn_mfma_f32_16x16x32_bf16(axh, bl0, z0, 0,0,0);
    z0 = __builtin_amdgcn_mfma_f32_16x16x32_bf16(axh, bh0, z0, 0,0,0);
    f32x4 z1 = __builtin_amdgcn_mfma_f32_16x16x32_bf16(axl, bh1, zero4, 0,0,0);
    z1 = __builtin_amdgcn_mfma_f32_16x16x32_bf16(axh, bl1, z1, 0,0,0);
    z1 = __builtin_amdgcn_mfma_f32_16x16x32_bf16(axh, bh1, z1, 0,0,0);
    ushort4 o0, o1v;
    o0.x  = f2h(fmaxf(z0[0] + b2v0, 0.f));
    o0.y  = f2h(fmaxf(z0[1] + b2v0, 0.f));
    o0.z  = f2h(fmaxf(z0[2] + b2v0, 0.f));
    o0.w  = f2h(fmaxf(z0[3] + b2v0, 0.f));
    o1v.x = f2h(fmaxf(z1[0] + b2v1, 0.f));
    o1v.y = f2h(fmaxf(z1[1] + b2v1, 0.f));
    o1v.z = f2h(fmaxf(z1[2] + b2v1, 0.f));
    o1v.w = f2h(fmaxf(z1[3] + b2v1, 0.f));
    *(ushort4*)&x2Lh[el*264      + wid*64 + p*16 + kg4] = o0;
    *(ushort4*)&x2Lh[(16+el)*264 + wid*64 + p*16 + kg4] = o1v;
  }
  // no barrier: producers/consumers are in the same wave (in-order LDS)

  // ---- A-side feature slices ----
  f32x4 h0a = *(const f32x4*)(P.h0c + (size_t)sidx*32 + isl);
  f32x4 h0b = *(const f32x4*)(P.h0c + (size_t)sidx*32 + isl + 4);
  float h1sl[24];
  {
    const float* hp = P.h1c + (size_t)sidx*96 + isl*3;
    #pragma unroll
    for (int q = 0; q < 6; ++q) {
      f32x4 v = *(const f32x4*)(hp + q*4);
      h1sl[q*4+0]=v[0]; h1sl[q*4+1]=v[1]; h1sl[q*4+2]=v[2]; h1sl[q*4+3]=v[3];
    }
  }

  bf16x8 a_h0;
  #pragma unroll
  for (int j = 0; j < 4; ++j) { a_h0[j] = f2bf(h0a[j]); a_h0[j+4] = f2bf(h0b[j]); }

  const int xrow = wid*64 + kg4;   // + p*16 -> slot of x2_p[edge kg4+r]

  // ---------------- P00: msg0 = b00 * (R00 . hs0) ----------------
  f32x4 macc0 = zero4;
  {
    const unsigned short* bb = P.B00 + el*32 + isl;
    #pragma unroll 4
    for (int t = 0; t < 32; ++t) {
      bf16x8 bv = *(const bf16x8*)(bb + t*512);
      f32x4 z = __builtin_amdgcn_mfma_f32_16x16x32_bf16(a_h0, bv, zero4, 0, 0, 0);
      f32x4 xs = CVT4(&x2Lh[t*264 + xrow + 0]);             // path 0
      macc0[0] = fmaf(xs[0], z[0], macc0[0]);
      macc0[1] = fmaf(xs[1], z[1], macc0[1]);
      macc0[2] = fmaf(xs[2], z[2], macc0[2]);
      macc0[3] = fmaf(xs[3], z[3], macc0[3]);
    }
  }
  { // scale by b00 per C-row edge (e = eb + kg4 + r)
    f32x4 bv = *(const f32x4*)(P.b00 + eb + kg4);
    macc0[0]*=bv[0]; macc0[1]*=bv[1]; macc0[2]*=bv[2]; macc0[3]*=bv[3];
  }

  // ---------------- P10: msg0 += R10 . t10 ----------------
  {
    const float* bp = P.b10 + (size_t)e*3;
    float c0 = bp[0], c1 = bp[1], c2 = bp[2];
    bf16x8 a_t;
    #pragma unroll
    for (int j = 0; j < 8; ++j)
      a_t[j] = f2bf(c0*h1sl[j*3+0] + c1*h1sl[j*3+1] + c2*h1sl[j*3+2]);
    const unsigned short* bb = P.B10 + el*32 + isl;
    #pragma unroll 4
    for (int t = 0; t < 32; ++t) {
      bf16x8 bv = *(const bf16x8*)(bb + t*512);
      f32x4 z = __builtin_amdgcn_mfma_f32_16x16x32_bf16(a_t, bv, zero4, 0, 0, 0);
      f32x4 xs = CVT4(&x2Lh[t*264 + xrow + 32]);            // path 2
      macc0[0] = fmaf(xs[0], z[0], macc0[0]);
      macc0[1] = fmaf(xs[1], z[1], macc0[1]);
      macc0[2] = fmaf(xs[2], z[2], macc0[2]);
      macc0[3] = fmaf(xs[3], z[3], macc0[3]);
    }
  }
  // store msg0 mean over 8 edges per dst
  {
    float s = macc0[0]+macc0[1]+macc0[2]+macc0[3];
    s += __shfl_xor(s, 16);
    if ((kg & 1) == 0)
      P.agg0[(size_t)((eb >> 3) + (kg >> 1))*16 + el] = s * 0.125f;
  }

  // ---------------- P01: msg1 = b01[m] * (R01 . hs0) ----------------
  f32x4 c01 = zero4;
  {
    const unsigned short* bb = P.B01 + el*32 + isl;
    #pragma unroll 4
    for (int t = 0; t < 32; ++t) {
      bf16x8 bv = *(const bf16x8*)(bb + t*512);
      f32x4 z = __builtin_amdgcn_mfma_f32_16x16x32_bf16(a_h0, bv, zero4, 0, 0, 0);
      f32x4 xs = CVT4(&x2Lh[t*264 + xrow + 16]);            // path 1
      c01[0] = fmaf(xs[0], z[0], c01[0]);
      c01[1] = fmaf(xs[1], z[1], c01[1]);
      c01[2] = fmaf(xs[2], z[2], c01[2]);
      c01[3] = fmaf(xs[3], z[3], c01[3]);
    }
  }
  f32x4 m1a, m1b, m1c;
  {
    const float* bp = P.b01 + (size_t)(eb + kg4)*3;   // 12 floats: rows kg4..kg4+3
    f32x4 q0 = *(const f32x4*)(bp);
    f32x4 q1 = *(const f32x4*)(bp + 4);
    f32x4 q2 = *(const f32x4*)(bp + 8);
    m1a[0]=c01[0]*q0[0]; m1a[1]=c01[1]*q0[3]; m1a[2]=c01[2]*q1[2]; m1a[3]=c01[3]*q2[1];
    m1b[0]=c01[0]*q0[1]; m1b[1]=c01[1]*q1[0]; m1b[2]=c01[2]*q1[3]; m1b[3]=c01[3]*q2[2];
    m1c[0]=c01[0]*q0[2]; m1c[1]=c01[1]*q1[1]; m1c[2]=c01[2]*q2[0]; m1c[3]=c01[3]*q2[3];
  }

  // ---------------- P11: msg1 += sum_f R11f . tmp_f ----------------
  {
    const float* b11e = P.b11 + (size_t)e*27;
    #pragma unroll 1
    for (int f = 0; f < 3; ++f) {
      float bm[9];
      #pragma unroll
      for (int mn = 0; mn < 9; ++mn) bm[mn] = b11e[mn*3 + f];
      bf16x8 am0, am1, am2;
      #pragma unroll
      for (int j = 0; j < 8; ++j) {
        float hn0 = h1sl[j*3+0], hn1 = h1sl[j*3+1], hn2 = h1sl[j*3+2];
        am0[j] = f2bf(bm[0]*hn0 + bm[1]*hn1 + bm[2]*hn2);
        am1[j] = f2bf(bm[3]*hn0 + bm[4]*hn1 + bm[5]*hn2);
        am2[j] = f2bf(bm[6]*hn0 + bm[7]*hn1 + bm[8]*hn2);
      }
      const unsigned short* bb = P.B11 + (size_t)f*16384 + el*32 + isl;
      #pragma unroll 4
      for (int t = 0; t < 32; ++t) {
        bf16x8 bv = *(const bf16x8*)(bb + t*512);
        f32x4 z0 = __builtin_amdgcn_mfma_f32_16x16x32_bf16(am0, bv, zero4, 0, 0, 0);
        f32x4 z1 = __builtin_amdgcn_mfma_f32_16x16x32_bf16(am1, bv, zero4, 0, 0, 0);
        f32x4 z2 = __builtin_amdgcn_mfma_f32_16x16x32_bf16(am2, bv, zero4, 0, 0, 0);
        f32x4 xs = CVT4(&x2Lh[t*264 + xrow + 48]);          // path 3
        m1a[0] = fmaf(xs[0], z0[0], m1a[0]);
        m1a[1] = fmaf(xs[1], z0[1], m1a[1]);
        m1a[2] = fmaf(xs[2], z0[2], m1a[2]);
        m1a[3] = fmaf(xs[3], z0[3], m1a[3]);
        m1b[0] = fmaf(xs[0], z1[0], m1b[0]);
        m1b[1] = fmaf(xs[1], z1[1], m1b[1]);
        m1b[2] = fmaf(xs[2], z1[2], m1b[2]);
        m1b[3] = fmaf(xs[3], z1[3], m1b[3]);
        m1c[0] = fmaf(xs[0], z2[0], m1c[0]);
        m1c[1] = fmaf(xs[1], z2[1], m1c[1]);
        m1c[2] = fmaf(xs[2], z2[2], m1c[2]);
        m1c[3] = fmaf(xs[3], z2[3], m1c[3]);
      }
    }
  }

  // store msg1 mean over 8 edges per dst
  {
    float sa = m1a[0]+m1a[1]+m1a[2]+m1a[3]; sa += __shfl_xor(sa, 16);
    float sb = m1b[0]+m1b[1]+m1b[2]+m1b[3]; sb += __shfl_xor(sb, 16);
    float sc = m1c[0]+m1c[1]+m1c[2]+m1c[3]; sc += __shfl_xor(sc, 16);
    if ((kg & 1) == 0) {
      float* p = P.agg1 + (size_t)((eb >> 3) + (kg >> 1))*48 + el*3;
      p[0] = sa * 0.125f; p[1] = sb * 0.125f; p[2] = sc * 0.125f;
    }
  }
}

// ---------------------------------------------------------------------------
// Kernel 3: self-interaction + GNormSE3, 4 lanes per node (passing).
// ---------------------------------------------------------------------------
__global__ __launch_bounds__(256) void gnorm_kernel(
    const float* __restrict__ agg0, const float* __restrict__ agg1,
    const float* __restrict__ h0c, const float* __restrict__ h1c,
    const float* __restrict__ ws0, const float* __restrict__ ws1,
    const float* __restrict__ g0, const float* __restrict__ be0,
    const float* __restrict__ g1, const float* __restrict__ be1,
    float* __restrict__ out)
{
  const int gt  = blockIdx.x * 256 + threadIdx.x;
  const int fi  = gt >> 2;
  const int t4  = gt & 3;
  const int ob  = t4 * 4;

  const float* h0p = h0c + (size_t)fi*32;
  const float* h1p = h1c + (size_t)fi*96;

  float o0[4];
  #pragma unroll
  for (int oo = 0; oo < 4; ++oo) {
    int o = ob + oo;
    float a = agg0[(size_t)fi*16 + o];
    #pragma unroll
    for (int i = 0; i < 32; ++i)
      a = fmaf(ws0[o*32+i], h0p[i], a);
    o0[oo] = a;
  }
  {
    float n0[4], lmu = 0.f;
    #pragma unroll
    for (int oo = 0; oo < 4; ++oo) { n0[oo] = sqrtf(fmaf(o0[oo], o0[oo], 1e-12f)); lmu += n0[oo]; }
    lmu += __shfl_xor(lmu, 1); lmu += __shfl_xor(lmu, 2);
    float mu = lmu * 0.0625f;
    float lv = 0.f;
    #pragma unroll
    for (int oo = 0; oo < 4; ++oo) { float d = n0[oo]-mu; lv = fmaf(d, d, lv); }
    lv += __shfl_xor(lv, 1); lv += __shfl_xor(lv, 2);
    float inv = 1.f / sqrtf(lv * 0.0625f + 1e-5f);
    #pragma unroll
    for (int oo = 0; oo < 4; ++oo) {
      int o = ob + oo;
      float t = fmaxf(fmaf((n0[oo]-mu)*inv, g0[o], be0[o]), 0.f);
      out[(size_t)fi*16 + o] = t * (o0[oo] / n0[oo]);
    }
  }

  float o1[12];
  #pragma unroll
  for (int oo = 0; oo < 4; ++oo) {
    int o = ob + oo;
    float a0 = agg1[(size_t)fi*48 + o*3+0];
    float a1 = agg1[(size_t)fi*48 + o*3+1];
    float a2 = agg1[(size_t)fi*48 + o*3+2];
    #pragma unroll
    for (int i = 0; i < 32; ++i) {
      float wv = ws1[o*32+i];
      a0 = fmaf(wv, h1p[i*3+0], a0);
      a1 = fmaf(wv, h1p[i*3+1], a1);
      a2 = fmaf(wv, h1p[i*3+2], a2);
    }
    o1[oo*3+0] = a0; o1[oo*3+1] = a1; o1[oo*3+2] = a2;
  }
  {
    float n1[4], lmu = 0.f;
    #pragma unroll
    for (int oo = 0; oo < 4; ++oo) {
      float s = fmaf(o1[oo*3+0], o1[oo*3+0], 1e-12f);
      s = fmaf(o1[oo*3+1], o1[oo*3+1], s);
      s = fmaf(o1[oo*3+2], o1[oo*3+2], s);
      n1[oo] = sqrtf(s); lmu += n1[oo];
    }
    lmu += __shfl_xor(lmu, 1); lmu += __shfl_xor(lmu, 2);
    float mu = lmu * 0.0625f;
    float lv = 0.f;
    #pragma unroll
    for (int oo = 0; oo < 4; ++oo) { float d = n1[oo]-mu; lv = fmaf(d, d, lv); }
    lv += __shfl_xor(lv, 1); lv += __shfl_xor(lv, 2);
    float inv = 1.f / sqrtf(lv * 0.0625f + 1e-5f);
    float* out1 = out + (size_t)BN*16;
    #pragma unroll
    for (int oo = 0; oo < 4; ++oo) {
      int o = ob + oo;
      float t = fmaxf(fmaf((n1[oo]-mu)*inv, g1[o], be1[o]), 0.f);
      #pragma unroll
      for (int m = 0; m < 3; ++m)
        out1[(size_t)fi*48 + o*3+m] = t * (o1[oo*3+m] / n1[oo]);
    }
  }
}

// ---------------------------------------------------------------------------
extern "C" void kernel_launch(void* const* d_in, const int* in_sizes, int n_in,
                              void* d_out, int out_size, void* d_ws, size_t ws_size,
                              hipStream_t stream)
{
  (void)in_sizes; (void)n_in; (void)out_size; (void)ws_size;
  const float* h0   = (const float*)d_in[0];
  const float* h1   = (const float*)d_in[1];
  const float* uph0 = (const float*)d_in[2];
  const float* uph1 = (const float*)d_in[3];
  const float* xyz  = (const float*)d_in[4];
  const float* xyzp = (const float*)d_in[5];
  const int*   esrc = (const int*)d_in[6];
  // d_in[7] = edge_dst: structurally e>>3; not needed.
  const float* rr   = (const float*)d_in[8];

  float* wsp  = (float*)d_ws;
  float* h0c  = wsp;                          // BN*32
  float* h1c  = h0c + (size_t)BN*32;          // BN*96
  float* agg0 = h1c + (size_t)BN*96;          // BN*16
  float* agg1 = agg0 + (size_t)BN*16;         // BN*48
  unsigned short* B00 = (unsigned short*)(agg1 + (size_t)BN*48);
  unsigned short* B01 = B00 + 16384;
  unsigned short* B10 = B01 + 16384;
  unsigned short* B11 = B10 + 16384;          // 49152
  unsigned short* W2H = B11 + 49152;          // 4096
  unsigned short* W2L = W2H + 4096;           // 4096

  prolog_kernel<<<BN/4 + 416, 256, 0, stream>>>(
      h0, h1, uph0, uph1, xyz, xyzp, h0c, h1c,
      (const float*)d_in[17], (const float*)d_in[22],
      (const float*)d_in[27], (const float*)d_in[32],
      (const float*)d_in[15], (const float*)d_in[20],
      (const float*)d_in[25], (const float*)d_in[30],
      B00, B01, B10, B11, W2H, W2L);

  EP P;
  P.r = rr; P.esrc = esrc;
  P.b00 = (const float*)d_in[9];  P.b01 = (const float*)d_in[10];
  P.b10 = (const float*)d_in[11]; P.b11 = (const float*)d_in[12];
  P.w1_00 = (const float*)d_in[13]; P.b1_00 = (const float*)d_in[14]; P.b2_00 = (const float*)d_in[16];
  P.w1_01 = (const float*)d_in[18]; P.b1_01 = (const float*)d_in[19]; P.b2_01 = (const float*)d_in[21];
  P.w1_10 = (const float*)d_in[23]; P.b1_10 = (const float*)d_in[24]; P.b2_10 = (const float*)d_in[26];
  P.w1_11 = (const float*)d_in[28]; P.b1_11 = (const float*)d_in[29]; P.b2_11 = (const float*)d_in[31];
  P.B00 = B00; P.B01 = B01; P.B10 = B10; P.B11 = B11; P.W2H = W2H; P.W2L = W2L;
  P.h0c = h0c; P.h1c = h1c; P.agg0 = agg0; P.agg1 = agg1;

  edge_mfma<<<NE/64, 256, 0, stream>>>(P);

  gnorm_kernel<<<BN*4/256, 256, 0, stream>>>(agg0, agg1, h0c, h1c,
      (const float*)d_in[33], (const float*)d_in[34],
      (const float*)d_in[35], (const float*)d_in[36],
      (const float*)d_in[37], (const float*)d_in[38],
      (float*)d_out);
}

// Round 13
// 99.744 us; speedup vs baseline: 1.1000x; 1.0342x over previous
//
#include <hip/hip_runtime.h>
#include <hip/hip_bf16.h>
#include <hip/hip_fp16.h>
#include <math.h>

#define NPP   1024
#define BN    8192     // BS*N
#define NE    65536    // BN*KDEG

typedef __attribute__((ext_vector_type(8))) short bf16x8;
typedef __attribute__((ext_vector_type(4))) float f32x4;

__device__ __forceinline__ short f2bf(float f) {
  __hip_bfloat16 h = __float2bfloat16(f);
  return *reinterpret_cast<short*>(&h);
}
__device__ __forceinline__ float b2f(short h) {
  unsigned u = ((unsigned)(unsigned short)h) << 16;
  return __uint_as_float(u);
}
__device__ __forceinline__ unsigned short f2h(float f) {
  __half h = __float2half(f);
  return *reinterpret_cast<unsigned short*>(&h);
}
__device__ __forceinline__ float h2f(unsigned short u) {
  __half h = *reinterpret_cast<__half*>(&u);
  return __half2float(h);
}

// ---------------------------------------------------------------------------
// Kernel 1 (fused prologue): blocks [0,2048) = three_nn+interp (wave/point);
// blocks [2048,2464) = weight repack to bf16. Independent outputs, no LDS.
// ---------------------------------------------------------------------------
__device__ __forceinline__ unsigned long long pkkey(float d, int j) {
  return ((unsigned long long)__float_as_uint(d) << 32) | (unsigned int)j;
}

__global__ __launch_bounds__(256) void prolog_kernel(
    const float* __restrict__ h0, const float* __restrict__ h1,
    const float* __restrict__ uph0, const float* __restrict__ uph1,
    const float* __restrict__ xyz, const float* __restrict__ xyzp,
    float* __restrict__ h0c, float* __restrict__ h1c,
    const float* __restrict__ w00, const float* __restrict__ w01,
    const float* __restrict__ w10, const float* __restrict__ w11,
    const float* __restrict__ w2_00, const float* __restrict__ w2_01,
    const float* __restrict__ w2_10, const float* __restrict__ w2_11,
    unsigned short* __restrict__ B00, unsigned short* __restrict__ B01,
    unsigned short* __restrict__ B10, unsigned short* __restrict__ B11,
    unsigned short* __restrict__ W2H, unsigned short* __restrict__ W2L)
{
  const int tid = threadIdx.x;
  if (blockIdx.x >= BN/4) {
    // ---------------- repack branch ----------------
    int idx = (blockIdx.x - BN/4) * 256 + tid;
    if (idx < 49152) {
      int a = idx & 16383;
      int i = a & 31, o = (a >> 5) & 15, k = a >> 9;
      int src = k*512 + o*32 + i;
      if (idx < 16384)      B00[a] = (unsigned short)f2bf(w00[src]);
      else if (idx < 32768) B01[a] = (unsigned short)f2bf(w01[src]);
      else                  B10[a] = (unsigned short)f2bf(w10[src]);
    } else if (idx < 98304) {
      int a = idx - 49152;                   // ((f*32+k)*16+o)*32+i
      int i = a & 31, o = (a >> 5) & 15, s = a >> 9;
      int f = s >> 5, k = s & 31;
      B11[a] = (unsigned short)f2bf(w11[k*1536 + (o*32+i)*3 + f]);
    } else if (idx < 102400) {
      int a = idx - 98304;                   // W2H: [p][b][a]
      int p = a >> 10, rem = a & 1023;
      int b = rem >> 5, aa = rem & 31;
      const float* w2p = p==0?w2_00 : p==1?w2_01 : p==2?w2_10 : w2_11;
      W2H[a] = (unsigned short)f2bf(w2p[aa*32 + b]);
    } else if (idx < 106496) {
      int a = idx - 102400;                  // W2L
      int p = a >> 10, rem = a & 1023;
      int b = rem >> 5, aa = rem & 31;
      const float* w2p = p==0?w2_00 : p==1?w2_01 : p==2?w2_10 : w2_11;
      float v = w2p[aa*32 + b];
      short h = f2bf(v);
      W2L[a] = (unsigned short)f2bf(v - b2f(h));
    }
    return;
  }

  // ---------------- interp branch (wave per fine point) ----------------
  const int lane = tid & 63;
  const int wid  = tid >> 6;
  const int fi   = blockIdx.x * 4 + wid;
  const int b    = fi >> 12;

  const float px = xyz[fi*3+0], py = xyz[fi*3+1], pz = xyz[fi*3+2];

  unsigned long long k0 = ~0ull, k1 = ~0ull, k2 = ~0ull;
  const float* cbase = xyzp + (size_t)b*NPP*3;
  #pragma unroll 4
  for (int j = lane; j < NPP; j += 64) {
    const float* cp = cbase + j*3;
    float ax = px - cp[0], ay = py - cp[1], az = pz - cp[2];
    float dd = fmaf(az, az, fmaf(ay, ay, ax*ax));
    unsigned long long kk = pkkey(dd, j);
    if (kk < k0)      { k2 = k1; k1 = k0; k0 = kk; }
    else if (kk < k1) { k2 = k1; k1 = kk; }
    else if (kk < k2) { k2 = kk; }
  }
  #pragma unroll
  for (int off = 1; off < 64; off <<= 1) {
    unsigned long long b0 = __shfl_xor(k0, off);
    unsigned long long b1 = __shfl_xor(k1, off);
    unsigned long long b2 = __shfl_xor(k2, off);
    unsigned long long c0, c1, c2;
    if (k0 <= b0) {
      c0 = k0;
      if (k1 <= b0) { c1 = k1; c2 = (k2 <= b0) ? k2 : b0; }
      else          { c1 = b0; c2 = (k1 <= b1) ? k1 : b1; }
    } else {
      c0 = b0;
      if (b1 <= k0) { c1 = b1; c2 = (b2 <= k0) ? b2 : k0; }
      else          { c1 = k0; c2 = (b1 <= k1) ? b1 : k1; }
    }
    k0 = c0; k1 = c1; k2 = c2;
  }
  const int i0 = (int)(k0 & 0xffffffffu);
  const int i1 = (int)(k1 & 0xffffffffu);
  const int i2 = (int)(k2 & 0xffffffffu);
  const float dd0 = __uint_as_float((unsigned)(k0 >> 32));
  const float dd1 = __uint_as_float((unsigned)(k1 >> 32));
  const float dd2 = __uint_as_float((unsigned)(k2 >> 32));

  float w0, w1v, w2v;
  {
    float s0 = sqrtf(fmaxf(dd0, 0.f));
    float s1 = sqrtf(fmaxf(dd1, 0.f));
    float s2 = sqrtf(fmaxf(dd2, 0.f));
    w0  = 1.f / (fmaxf(s0*s0, 1e-10f) + 1e-8f);
    w1v = 1.f / (fmaxf(s1*s1, 1e-10f) + 1e-8f);
    w2v = 1.f / (fmaxf(s2*s2, 1e-10f) + 1e-8f);
    float wsum = w0 + w1v + w2v;
    w0 /= wsum; w1v /= wsum; w2v /= wsum;
  }

  const float* u0 = uph0 + (size_t)b*NPP*16;
  const float* u1 = uph1 + (size_t)b*NPP*48;
  if (lane < 16) {
    int c = lane;
    h0c[(size_t)fi*32 + c] = w0*u0[i0*16+c] + w1v*u0[i1*16+c] + w2v*u0[i2*16+c];
    h0c[(size_t)fi*32 + 16 + c] = h0[(size_t)fi*16 + c];
  } else {
    int q = lane - 16;
    h1c[(size_t)fi*96 + q] = w0*u1[i0*48+q] + w1v*u1[i1*48+q] + w2v*u1[i2*48+q];
    h1c[(size_t)fi*96 + 48 + q] = h1[(size_t)fi*48 + q];
  }
}

// ---------------------------------------------------------------------------
// Kernel 2: MFMA edge kernel — R10 structure; loops merged for MLP:
//  - f=1 paths (B00/B01/B10) in ONE t-loop (3 loads/step, unroll 2)
//  - P11's three f-planes in ONE t-loop (3 loads/step, unroll 4)
// Per-accumulator summation order unchanged (separate accumulators).
// ---------------------------------------------------------------------------
struct EP {
  const float *r; const int *esrc;
  const float *b00, *b01, *b10, *b11;
  const float *w1_00, *b1_00, *b2_00;
  const float *w1_01, *b1_01, *b2_01;
  const float *w1_10, *b1_10, *b2_10;
  const float *w1_11, *b1_11, *b2_11;
  const unsigned short *B00, *B01, *B10, *B11, *W2H, *W2L;
  const float *h0c, *h1c;
  float *agg0, *agg1;
};

#define CVT4(PTR) ({ ushort4 u_ = *(const ushort4*)(PTR); \
    f32x4 r_; r_[0]=h2f(u_.x); r_[1]=h2f(u_.y); r_[2]=h2f(u_.z); r_[3]=h2f(u_.w); r_; })

__global__ __launch_bounds__(256) void edge_mfma(EP P)
{
  // [t(32 ch)][wid(4)][p(4)][e(16)] f16, row stride 264 shorts (pad 8)
  __shared__ __align__(16) unsigned short x2Lh[32*264];

  const int tid  = threadIdx.x;
  const int wid  = tid >> 6;
  const int lane = tid & 63;
  const int el   = lane & 15;
  const int kg   = lane >> 4;
  const int kg4  = kg << 2;
  const int eb   = blockIdx.x * 64 + wid * 16;
  const int e    = eb + el;
  const int isl  = kg * 8;

  const int   sidx = P.esrc[e];
  const float rv   = P.r[e];

  const f32x4 zero4 = {0.f, 0.f, 0.f, 0.f};

  // ---- radial MLPs via split-precision MFMA, x2 -> f16 LDS table ----
  #pragma unroll
  for (int p = 0; p < 4; ++p) {
    const float* w1p = p==0?P.w1_00 : p==1?P.w1_01 : p==2?P.w1_10 : P.w1_11;
    const float* b1p = p==0?P.b1_00 : p==1?P.b1_01 : p==2?P.b1_10 : P.b1_11;
    const float* b2p = p==0?P.b2_00 : p==1?P.b2_01 : p==2?P.b2_10 : P.b2_11;
    const unsigned short* w2hp = P.W2H + p*1024;
    const unsigned short* w2lp = P.W2L + p*1024;
    f32x4 wa  = *(const f32x4*)(w1p + isl);
    f32x4 wb  = *(const f32x4*)(w1p + isl + 4);
    f32x4 ba  = *(const f32x4*)(b1p + isl);
    f32x4 bbv = *(const f32x4*)(b1p + isl + 4);
    bf16x8 bh0 = *(const bf16x8*)(w2hp + el*32 + isl);
    bf16x8 bh1 = *(const bf16x8*)(w2hp + (16+el)*32 + isl);
    bf16x8 bl0 = *(const bf16x8*)(w2lp + el*32 + isl);
    bf16x8 bl1 = *(const bf16x8*)(w2lp + (16+el)*32 + isl);
    float b2v0 = b2p[el];
    float b2v1 = b2p[16 + el];
    bf16x8 axh, axl;
    #pragma unroll
    for (int j = 0; j < 4; ++j) {
      float v0 = fmaxf(fmaf(rv, wa[j], ba[j]),  0.f);
      float v1 = fmaxf(fmaf(rv, wb[j], bbv[j]), 0.f);
      short h0s = f2bf(v0), h1s_ = f2bf(v1);
      axh[j]   = h0s;  axl[j]   = f2bf(v0 - b2f(h0s));
      axh[j+4] = h1s_; axl[j+4] = f2bf(v1 - b2f(h1s_));
    }
    f32x4 z0 = __builtin_amdgcn_mfma_f32_16x16x32_bf16(axl, bh0, zero4, 0,0,0);
    z0 = __builtin_amdgcn_mfma_f32_16x16x32_bf16(axh, bl0, z0, 0,0,0);
    z0 = __builtin_amdgcn_mfma_f32_16x16x32_bf16(axh, bh0, z0, 0,0,0);
    f32x4 z1 = __builtin_amdgcn_mfma_f32_16x16x32_bf16(axl, bh1, zero4, 0,0,0);
    z1 = __builtin_amdgcn_mfma_f32_16x16x32_bf16(axh, bl1, z1, 0,0,0);
    z1 = __builtin_amdgcn_mfma_f32_16x16x32_bf16(axh, bh1, z1, 0,0,0);
    ushort4 o0, o1v;
    o0.x  = f2h(fmaxf(z0[0] + b2v0, 0.f));
    o0.y  = f2h(fmaxf(z0[1] + b2v0, 0.f));
    o0.z  = f2h(fmaxf(z0[2] + b2v0, 0.f));
    o0.w  = f2h(fmaxf(z0[3] + b2v0, 0.f));
    o1v.x = f2h(fmaxf(z1[0] + b2v1, 0.f));
    o1v.y = f2h(fmaxf(z1[1] + b2v1, 0.f));
    o1v.z = f2h(fmaxf(z1[2] + b2v1, 0.f));
    o1v.w = f2h(fmaxf(z1[3] + b2v1, 0.f));
    *(ushort4*)&x2Lh[el*264      + wid*64 + p*16 + kg4] = o0;
    *(ushort4*)&x2Lh[(16+el)*264 + wid*64 + p*16 + kg4] = o1v;
  }
  // no barrier: producers/consumers are in the same wave (in-order LDS)

  // ---- A-side feature slices ----
  f32x4 h0a = *(const f32x4*)(P.h0c + (size_t)sidx*32 + isl);
  f32x4 h0b = *(const f32x4*)(P.h0c + (size_t)sidx*32 + isl + 4);
  float h1sl[24];
  {
    const float* hp = P.h1c + (size_t)sidx*96 + isl*3;
    #pragma unroll
    for (int q = 0; q < 6; ++q) {
      f32x4 v = *(const f32x4*)(hp + q*4);
      h1sl[q*4+0]=v[0]; h1sl[q*4+1]=v[1]; h1sl[q*4+2]=v[2]; h1sl[q*4+3]=v[3];
    }
  }

  bf16x8 a_h0;
  #pragma unroll
  for (int j = 0; j < 4; ++j) { a_h0[j] = f2bf(h0a[j]); a_h0[j+4] = f2bf(h0b[j]); }

  bf16x8 a_t;
  {
    const float* bp = P.b10 + (size_t)e*3;
    float c0 = bp[0], c1 = bp[1], c2 = bp[2];
    #pragma unroll
    for (int j = 0; j < 8; ++j)
      a_t[j] = f2bf(c0*h1sl[j*3+0] + c1*h1sl[j*3+1] + c2*h1sl[j*3+2]);
  }

  const int xrow = wid*64 + kg4;   // + p*16 -> slot of x2_p[edge kg4+r]

  // -------- merged f=1 paths: P00 + P01 + P10 in one t-loop --------
  f32x4 macc00 = zero4, c01 = zero4, macc10 = zero4;
  {
    const unsigned short* bb00 = P.B00 + el*32 + isl;
    const unsigned short* bb01 = P.B01 + el*32 + isl;
    const unsigned short* bb10 = P.B10 + el*32 + isl;
    #pragma unroll 2
    for (int t = 0; t < 32; ++t) {
      bf16x8 bv00 = *(const bf16x8*)(bb00 + t*512);
      bf16x8 bv01 = *(const bf16x8*)(bb01 + t*512);
      bf16x8 bv10 = *(const bf16x8*)(bb10 + t*512);
      f32x4 xs0 = CVT4(&x2Lh[t*264 + xrow + 0]);
      f32x4 xs1 = CVT4(&x2Lh[t*264 + xrow + 16]);
      f32x4 xs2 = CVT4(&x2Lh[t*264 + xrow + 32]);
      f32x4 z00 = __builtin_amdgcn_mfma_f32_16x16x32_bf16(a_h0, bv00, zero4, 0, 0, 0);
      f32x4 z01 = __builtin_amdgcn_mfma_f32_16x16x32_bf16(a_h0, bv01, zero4, 0, 0, 0);
      f32x4 z10 = __builtin_amdgcn_mfma_f32_16x16x32_bf16(a_t,  bv10, zero4, 0, 0, 0);
      macc00[0] = fmaf(xs0[0], z00[0], macc00[0]);
      macc00[1] = fmaf(xs0[1], z00[1], macc00[1]);
      macc00[2] = fmaf(xs0[2], z00[2], macc00[2]);
      macc00[3] = fmaf(xs0[3], z00[3], macc00[3]);
      c01[0] = fmaf(xs1[0], z01[0], c01[0]);
      c01[1] = fmaf(xs1[1], z01[1], c01[1]);
      c01[2] = fmaf(xs1[2], z01[2], c01[2]);
      c01[3] = fmaf(xs1[3], z01[3], c01[3]);
      macc10[0] = fmaf(xs2[0], z10[0], macc10[0]);
      macc10[1] = fmaf(xs2[1], z10[1], macc10[1]);
      macc10[2] = fmaf(xs2[2], z10[2], macc10[2]);
      macc10[3] = fmaf(xs2[3], z10[3], macc10[3]);
    }
  }
  // msg0 = b00 * Sum(P00) + Sum(P10); store mean over 8 edges per dst
  {
    f32x4 bv = *(const f32x4*)(P.b00 + eb + kg4);
    float s = fmaf(bv[0], macc00[0], macc10[0])
            + fmaf(bv[1], macc00[1], macc10[1])
            + fmaf(bv[2], macc00[2], macc10[2])
            + fmaf(bv[3], macc00[3], macc10[3]);
    s += __shfl_xor(s, 16);
    if ((kg & 1) == 0)
      P.agg0[(size_t)((eb >> 3) + (kg >> 1))*16 + el] = s * 0.125f;
  }

  f32x4 m1a, m1b, m1c;
  {
    const float* bp = P.b01 + (size_t)(eb + kg4)*3;   // 12 floats: rows kg4..kg4+3
    f32x4 q0 = *(const f32x4*)(bp);
    f32x4 q1 = *(const f32x4*)(bp + 4);
    f32x4 q2 = *(const f32x4*)(bp + 8);
    m1a[0]=c01[0]*q0[0]; m1a[1]=c01[1]*q0[3]; m1a[2]=c01[2]*q1[2]; m1a[3]=c01[3]*q2[1];
    m1b[0]=c01[0]*q0[1]; m1b[1]=c01[1]*q1[0]; m1b[2]=c01[2]*q1[3]; m1b[3]=c01[3]*q2[2];
    m1c[0]=c01[0]*q0[2]; m1c[1]=c01[1]*q1[1]; m1c[2]=c01[2]*q2[0]; m1c[3]=c01[3]*q2[3];
  }

  // -------- P11: three f-planes merged into one t-loop --------
  {
    bf16x8 am[3][3];
    const float* b11e = P.b11 + (size_t)e*27;
    #pragma unroll
    for (int f = 0; f < 3; ++f) {
      float bm[9];
      #pragma unroll
      for (int mn = 0; mn < 9; ++mn) bm[mn] = b11e[mn*3 + f];
      #pragma unroll
      for (int j = 0; j < 8; ++j) {
        float hn0 = h1sl[j*3+0], hn1 = h1sl[j*3+1], hn2 = h1sl[j*3+2];
        am[f][0][j] = f2bf(bm[0]*hn0 + bm[1]*hn1 + bm[2]*hn2);
        am[f][1][j] = f2bf(bm[3]*hn0 + bm[4]*hn1 + bm[5]*hn2);
        am[f][2][j] = f2bf(bm[6]*hn0 + bm[7]*hn1 + bm[8]*hn2);
      }
    }
    const unsigned short* bb = P.B11 + el*32 + isl;
    #pragma unroll 4
    for (int t = 0; t < 32; ++t) {
      bf16x8 bv0 = *(const bf16x8*)(bb + t*512);
      bf16x8 bv1 = *(const bf16x8*)(bb + 16384 + t*512);
      bf16x8 bv2 = *(const bf16x8*)(bb + 32768 + t*512);
      f32x4 xs = CVT4(&x2Lh[t*264 + xrow + 48]);
      #pragma unroll
      for (int f = 0; f < 3; ++f) {
        bf16x8 bv = f==0 ? bv0 : (f==1 ? bv1 : bv2);
        f32x4 z0 = __builtin_amdgcn_mfma_f32_16x16x32_bf16(am[f][0], bv, zero4, 0, 0, 0);
        f32x4 z1 = __builtin_amdgcn_mfma_f32_16x16x32_bf16(am[f][1], bv, zero4, 0, 0, 0);
        f32x4 z2 = __builtin_amdgcn_mfma_f32_16x16x32_bf16(am[f][2], bv, zero4, 0, 0, 0);
        m1a[0] = fmaf(xs[0], z0[0], m1a[0]);
        m1a[1] = fmaf(xs[1], z0[1], m1a[1]);
        m1a[2] = fmaf(xs[2], z0[2], m1a[2]);
        m1a[3] = fmaf(xs[3], z0[3], m1a[3]);
        m1b[0] = fmaf(xs[0], z1[0], m1b[0]);
        m1b[1] = fmaf(xs[1], z1[1], m1b[1]);
        m1b[2] = fmaf(xs[2], z1[2], m1b[2]);
        m1b[3] = fmaf(xs[3], z1[3], m1b[3]);
        m1c[0] = fmaf(xs[0], z2[0], m1c[0]);
        m1c[1] = fmaf(xs[1], z2[1], m1c[1]);
        m1c[2] = fmaf(xs[2], z2[2], m1c[2]);
        m1c[3] = fmaf(xs[3], z2[3], m1c[3]);
      }
    }
  }

  // store msg1 mean over 8 edges per dst
  {
    float sa = m1a[0]+m1a[1]+m1a[2]+m1a[3]; sa += __shfl_xor(sa, 16);
    float sb = m1b[0]+m1b[1]+m1b[2]+m1b[3]; sb += __shfl_xor(sb, 16);
    float sc = m1c[0]+m1c[1]+m1c[2]+m1c[3]; sc += __shfl_xor(sc, 16);
    if ((kg & 1) == 0) {
      float* p = P.agg1 + (size_t)((eb >> 3) + (kg >> 1))*48 + el*3;
      p[0] = sa * 0.125f; p[1] = sb * 0.125f; p[2] = sc * 0.125f;
    }
  }
}

// ---------------------------------------------------------------------------
// Kernel 3: self-interaction + GNormSE3, 4 lanes per node (passing).
// ---------------------------------------------------------------------------
__global__ __launch_bounds__(256) void gnorm_kernel(
    const float* __restrict__ agg0, const float* __restrict__ agg1,
    const float* __restrict__ h0c, const float* __restrict__ h1c,
    const float* __restrict__ ws0, const float* __restrict__ ws1,
    const float* __restrict__ g0, const float* __restrict__ be0,
    const float* __restrict__ g1, const float* __restrict__ be1,
    float* __restrict__ out)
{
  const int gt  = blockIdx.x * 256 + threadIdx.x;
  const int fi  = gt >> 2;
  const int t4  = gt & 3;
  const int ob  = t4 * 4;

  const float* h0p = h0c + (size_t)fi*32;
  const float* h1p = h1c + (size_t)fi*96;

  float o0[4];
  #pragma unroll
  for (int oo = 0; oo < 4; ++oo) {
    int o = ob + oo;
    float a = agg0[(size_t)fi*16 + o];
    #pragma unroll
    for (int i = 0; i < 32; ++i)
      a = fmaf(ws0[o*32+i], h0p[i], a);
    o0[oo] = a;
  }
  {
    float n0[4], lmu = 0.f;
    #pragma unroll
    for (int oo = 0; oo < 4; ++oo) { n0[oo] = sqrtf(fmaf(o0[oo], o0[oo], 1e-12f)); lmu += n0[oo]; }
    lmu += __shfl_xor(lmu, 1); lmu += __shfl_xor(lmu, 2);
    float mu = lmu * 0.0625f;
    float lv = 0.f;
    #pragma unroll
    for (int oo = 0; oo < 4; ++oo) { float d = n0[oo]-mu; lv = fmaf(d, d, lv); }
    lv += __shfl_xor(lv, 1); lv += __shfl_xor(lv, 2);
    float inv = 1.f / sqrtf(lv * 0.0625f + 1e-5f);
    #pragma unroll
    for (int oo = 0; oo < 4; ++oo) {
      int o = ob + oo;
      float t = fmaxf(fmaf((n0[oo]-mu)*inv, g0[o], be0[o]), 0.f);
      out[(size_t)fi*16 + o] = t * (o0[oo] / n0[oo]);
    }
  }

  float o1[12];
  #pragma unroll
  for (int oo = 0; oo < 4; ++oo) {
    int o = ob + oo;
    float a0 = agg1[(size_t)fi*48 + o*3+0];
    float a1 = agg1[(size_t)fi*48 + o*3+1];
    float a2 = agg1[(size_t)fi*48 + o*3+2];
    #pragma unroll
    for (int i = 0; i < 32; ++i) {
      float wv = ws1[o*32+i];
      a0 = fmaf(wv, h1p[i*3+0], a0);
      a1 = fmaf(wv, h1p[i*3+1], a1);
      a2 = fmaf(wv, h1p[i*3+2], a2);
    }
    o1[oo*3+0] = a0; o1[oo*3+1] = a1; o1[oo*3+2] = a2;
  }
  {
    float n1[4], lmu = 0.f;
    #pragma unroll
    for (int oo = 0; oo < 4; ++oo) {
      float s = fmaf(o1[oo*3+0], o1[oo*3+0], 1e-12f);
      s = fmaf(o1[oo*3+1], o1[oo*3+1], s);
      s = fmaf(o1[oo*3+2], o1[oo*3+2], s);
      n1[oo] = sqrtf(s); lmu += n1[oo];
    }
    lmu += __shfl_xor(lmu, 1); lmu += __shfl_xor(lmu, 2);
    float mu = lmu * 0.0625f;
    float lv = 0.f;
    #pragma unroll
    for (int oo = 0; oo < 4; ++oo) { float d = n1[oo]-mu; lv = fmaf(d, d, lv); }
    lv += __shfl_xor(lv, 1); lv += __shfl_xor(lv, 2);
    float inv = 1.f / sqrtf(lv * 0.0625f + 1e-5f);
    float* out1 = out + (size_t)BN*16;
    #pragma unroll
    for (int oo = 0; oo < 4; ++oo) {
      int o = ob + oo;
      float t = fmaxf(fmaf((n1[oo]-mu)*inv, g1[o], be1[o]), 0.f);
      #pragma unroll
      for (int m = 0; m < 3; ++m)
        out1[(size_t)fi*48 + o*3+m] = t * (o1[oo*3+m] / n1[oo]);
    }
  }
}

// ---------------------------------------------------------------------------
extern "C" void kernel_launch(void* const* d_in, const int* in_sizes, int n_in,
                              void* d_out, int out_size, void* d_ws, size_t ws_size,
                              hipStream_t stream)
{
  (void)in_sizes; (void)n_in; (void)out_size; (void)ws_size;
  const float* h0   = (const float*)d_in[0];
  const float* h1   = (const float*)d_in[1];
  const float* uph0 = (const float*)d_in[2];
  const float* uph1 = (const float*)d_in[3];
  const float* xyz  = (const float*)d_in[4];
  const float* xyzp = (const float*)d_in[5];
  const int*   esrc = (const int*)d_in[6];
  // d_in[7] = edge_dst: structurally e>>3; not needed.
  const float* rr   = (const float*)d_in[8];

  float* wsp  = (float*)d_ws;
  float* h0c  = wsp;                          // BN*32
  float* h1c  = h0c + (size_t)BN*32;          // BN*96
  float* agg0 = h1c + (size_t)BN*96;          // BN*16
  float* agg1 = agg0 + (size_t)BN*16;         // BN*48
  unsigned short* B00 = (unsigned short*)(agg1 + (size_t)BN*48);
  unsigned short* B01 = B00 + 16384;
  unsigned short* B10 = B01 + 16384;
  unsigned short* B11 = B10 + 16384;          // 49152
  unsigned short* W2H = B11 + 49152;          // 4096
  unsigned short* W2L = W2H + 4096;           // 4096

  prolog_kernel<<<BN/4 + 416, 256, 0, stream>>>(
      h0, h1, uph0, uph1, xyz, xyzp, h0c, h1c,
      (const float*)d_in[17], (const float*)d_in[22],
      (const float*)d_in[27], (const float*)d_in[32],
      (const float*)d_in[15], (const float*)d_in[20],
      (const float*)d_in[25], (const float*)d_in[30],
      B00, B01, B10, B11, W2H, W2L);

  EP P;
  P.r = rr; P.esrc = esrc;
  P.b00 = (const float*)d_in[9];  P.b01 = (const float*)d_in[10];
  P.b10 = (const float*)d_in[11]; P.b11 = (const float*)d_in[12];
  P.w1_00 = (const float*)d_in[13]; P.b1_00 = (const float*)d_in[14]; P.b2_00 = (const float*)d_in[16];
  P.w1_01 = (const float*)d_in[18]; P.b1_01 = (const float*)d_in[19]; P.b2_01 = (const float*)d_in[21];
  P.w1_10 = (const float*)d_in[23]; P.b1_10 = (const float*)d_in[24]; P.b2_10 = (const float*)d_in[26];
  P.w1_11 = (const float*)d_in[28]; P.b1_11 = (const float*)d_in[29]; P.b2_11 = (const float*)d_in[31];
  P.B00 = B00; P.B01 = B01; P.B10 = B10; P.B11 = B11; P.W2H = W2H; P.W2L = W2L;
  P.h0c = h0c; P.h1c = h1c; P.agg0 = agg0; P.agg1 = agg1;

  edge_mfma<<<NE/64, 256, 0, stream>>>(P);

  gnorm_kernel<<<BN*4/256, 256, 0, stream>>>(agg0, agg1, h0c, h1c,
      (const float*)d_in[33], (const float*)d_in[34],
      (const float*)d_in[35], (const float*)d_in[36],
      (const float*)d_in[37], (const float*)d_in[38],
      (float*)d_out);
}